// Round 1
// baseline (619.785 us; speedup 1.0000x reference)
//
#include <hip/hip_runtime.h>
#include <hip/hip_bf16.h>

#define N_NODES 100000
#define N_EDGES 1600000

typedef unsigned short ushort_t;
typedef unsigned int uint_t;
typedef __bf16 bf16x8 __attribute__((ext_vector_type(8)));
typedef float f32x4 __attribute__((ext_vector_type(4)));

__device__ __forceinline__ float bf2f(uint_t u) {
    union { uint_t i; float f; } v; v.i = u << 16; return v.f;
}
__device__ __forceinline__ ushort_t f2bf(float f) {
    uint_t x = __float_as_uint(f);
    uint_t r = (x + 0x7fffu + ((x >> 16) & 1u)) >> 16;
    return (ushort_t)r;
}

// ---------------- CSR build ----------------

__global__ void k_hist(const int* __restrict__ dst, int* __restrict__ deg) {
    int e = blockIdx.x * 256 + threadIdx.x;   // E == 6250*256 exactly
    atomicAdd(&deg[dst[e]], 1);
}

__global__ void k_block_reduce(const int* __restrict__ deg, int* __restrict__ bsums) {
    __shared__ int sm[256];
    int t = threadIdx.x;
    int n = blockIdx.x * 256 + t;
    int v = (n < N_NODES) ? deg[n] : 0;
    sm[t] = v; __syncthreads();
    for (int off = 128; off > 0; off >>= 1) {
        if (t < off) sm[t] += sm[t + off];
        __syncthreads();
    }
    if (t == 0) bsums[blockIdx.x] = sm[0];
}

__global__ void k_top_scan(int* __restrict__ bsums, int nb) {
    __shared__ int sm[512];
    int t = threadIdx.x;
    int v = (t < nb) ? bsums[t] : 0;
    sm[t] = v; __syncthreads();
    for (int off = 1; off < 512; off <<= 1) {
        int x = (t >= off) ? sm[t - off] : 0;
        __syncthreads();
        sm[t] += x;
        __syncthreads();
    }
    if (t < nb) bsums[t] = sm[t] - v;   // exclusive
}

__global__ void k_scan_final(const int* __restrict__ deg, const int* __restrict__ bsums,
                             int* __restrict__ row_start, int* __restrict__ cursor) {
    __shared__ int sm[256];
    int t = threadIdx.x;
    int n = blockIdx.x * 256 + t;
    int v = (n < N_NODES) ? deg[n] : 0;
    sm[t] = v; __syncthreads();
    for (int off = 1; off < 256; off <<= 1) {
        int x = (t >= off) ? sm[t - off] : 0;
        __syncthreads();
        sm[t] += x;
        __syncthreads();
    }
    int excl = bsums[blockIdx.x] + sm[t] - v;
    if (n < N_NODES) { row_start[n] = excl; cursor[n] = excl; }
    if (n == 0) row_start[N_NODES] = N_EDGES;
}

__global__ void k_fill(const int* __restrict__ src, const int* __restrict__ dst,
                       int* __restrict__ cursor, int* __restrict__ col) {
    int e = blockIdx.x * 256 + threadIdx.x;
    int p = atomicAdd(&cursor[dst[e]], 1);
    col[p] = src[e];
}

// ---------------- conversions ----------------

__global__ void k_cvt_x(const float* __restrict__ x, ushort_t* __restrict__ h) {
    int i = (blockIdx.x * 256 + threadIdx.x) * 4;   // N*128 == 12500*256*4 exactly
    float4 v = *(const float4*)(x + i);
    uint2 o;
    o.x = (uint_t)f2bf(v.x) | ((uint_t)f2bf(v.y) << 16);
    o.y = (uint_t)f2bf(v.z) | ((uint_t)f2bf(v.w) << 16);
    *(uint2*)(h + i) = o;
}

// Wt layout: [do][256] bf16, k-major (rows 0..127 of k = W_self, 128..255 = W_neigh)
__global__ void k_cvt_w(const float* __restrict__ ws0, const float* __restrict__ wn0,
                        const float* __restrict__ ws1, const float* __restrict__ wn1,
                        const float* __restrict__ ws2, const float* __restrict__ wn2,
                        ushort_t* __restrict__ wt0, ushort_t* __restrict__ wt1,
                        ushort_t* __restrict__ wt2) {
    int idx = blockIdx.x * 256 + threadIdx.x;   // 0..81919 (320 blocks)
    const float *Ws, *Wn; ushort_t* Wt; int DO_; int local;
    if (idx < 32768)      { Ws = ws0; Wn = wn0; Wt = wt0; DO_ = 128; local = idx; }
    else if (idx < 65536) { Ws = ws1; Wn = wn1; Wt = wt1; DO_ = 128; local = idx - 32768; }
    else                  { Ws = ws2; Wn = wn2; Wt = wt2; DO_ = 64;  local = idx - 65536; }
    int n = local >> 8, k = local & 255;
    if (n < DO_) {
        float v = (k < 128) ? Ws[k * DO_ + n] : Wn[(k - 128) * DO_ + n];
        Wt[n * 256 + k] = f2bf(v);
    }
}

// ---------------- aggregation (gather-mean) ----------------

__global__ void k_agg(const ushort_t* __restrict__ h, const int* __restrict__ rs,
                      const int* __restrict__ col, ushort_t* __restrict__ out) {
    int node = blockIdx.x * 4 + (threadIdx.x >> 6);   // 25000*4 == N exactly
    int lane = threadIdx.x & 63;
    int beg = rs[node], end = rs[node + 1];
    float a0 = 0.f, a1 = 0.f;
    int i = beg;
    for (; i + 4 <= end; i += 4) {
        int s0 = col[i], s1 = col[i + 1], s2 = col[i + 2], s3 = col[i + 3];
        uint_t v0 = *(const uint_t*)(h + s0 * 128 + lane * 2);
        uint_t v1 = *(const uint_t*)(h + s1 * 128 + lane * 2);
        uint_t v2 = *(const uint_t*)(h + s2 * 128 + lane * 2);
        uint_t v3 = *(const uint_t*)(h + s3 * 128 + lane * 2);
        a0 += bf2f(v0 & 0xffffu) + bf2f(v1 & 0xffffu) + bf2f(v2 & 0xffffu) + bf2f(v3 & 0xffffu);
        a1 += bf2f(v0 >> 16) + bf2f(v1 >> 16) + bf2f(v2 >> 16) + bf2f(v3 >> 16);
    }
    for (; i < end; ++i) {
        uint_t v = *(const uint_t*)(h + col[i] * 128 + lane * 2);
        a0 += bf2f(v & 0xffffu); a1 += bf2f(v >> 16);
    }
    int d = end - beg;
    float inv = (d > 0) ? 1.0f / (float)d : 0.f;
    a0 *= inv; a1 *= inv;
    uint_t o = (uint_t)f2bf(a0) | ((uint_t)f2bf(a1) << 16);
    *(uint_t*)(out + node * 128 + lane * 2) = o;
}

// ---------------- fused dual-GEMM + bias (+ReLU) ----------------
// out[M,do] = hs[M,128] @ Ws + hn[M,128] @ Wn + b ; Wcat pre-transposed [do][256] bf16

template <int DOv, bool RELU, bool OUTF32>
__global__ __launch_bounds__(256) void k_gemm(const ushort_t* __restrict__ hs,
                                              const ushort_t* __restrict__ hn,
                                              const ushort_t* __restrict__ wt,
                                              const float* __restrict__ bias,
                                              ushort_t* __restrict__ hout,
                                              float* __restrict__ fout) {
    constexpr int NT = DOv / 16;
    __shared__ ushort_t lds_w[DOv][264];   // +8 elem pad: 528B pitch -> 2-way (free) LDS conflicts
    const int t = threadIdx.x;
    constexpr int CHUNKS = DOv * 32;       // 16B chunks
    for (int c = t; c < CHUNKS; c += 256) {
        int r = c >> 5, o = c & 31;
        *(uint4*)(&lds_w[r][o * 8]) = *(const uint4*)(wt + r * 256 + o * 8);
    }
    __syncthreads();

    int wid = t >> 6, lane = t & 63;
    int row0 = blockIdx.x * 64 + wid * 16;
    int arow = row0 + (lane & 15);
    if (arow >= N_NODES) arow = N_NODES - 1;
    int hi = lane >> 4;   // 0..3

    f32x4 acc[NT];
#pragma unroll
    for (int n = 0; n < NT; n++) acc[n] = (f32x4){0.f, 0.f, 0.f, 0.f};

#pragma unroll
    for (int kk = 0; kk < 8; kk++) {
        const ushort_t* hp = (kk < 4) ? hs : hn;
        int kloc = (kk & 3) * 32 + hi * 8;
        bf16x8 a = *(const bf16x8*)(hp + arow * 128 + kloc);
#pragma unroll
        for (int n = 0; n < NT; n++) {
            bf16x8 b = *(const bf16x8*)(&lds_w[n * 16 + (lane & 15)][kk * 32 + hi * 8]);
            acc[n] = __builtin_amdgcn_mfma_f32_16x16x32_bf16(a, b, acc[n], 0, 0, 0);
        }
    }

#pragma unroll
    for (int n = 0; n < NT; n++) {
        int colc = n * 16 + (lane & 15);
        float bv = bias[colc];
#pragma unroll
        for (int j = 0; j < 4; j++) {
            int row = row0 + hi * 4 + j;
            if (row < N_NODES) {
                float v = acc[n][j] + bv;
                if (RELU) v = v > 0.f ? v : 0.f;
                if (OUTF32) fout[row * DOv + colc] = v;
                else        hout[row * 128 + colc] = f2bf(v);
            }
        }
    }
}

// ---------------- launch ----------------

extern "C" void kernel_launch(void* const* d_in, const int* in_sizes, int n_in,
                              void* d_out, int out_size, void* d_ws, size_t ws_size,
                              hipStream_t stream) {
    const float* x   = (const float*)d_in[0];
    const int*   src = (const int*)d_in[1];
    const int*   dst = (const int*)d_in[2];
    const float* ws0 = (const float*)d_in[3];
    const float* wn0 = (const float*)d_in[4];
    const float* b0  = (const float*)d_in[5];
    const float* ws1 = (const float*)d_in[6];
    const float* wn1 = (const float*)d_in[7];
    const float* b1  = (const float*)d_in[8];
    const float* ws2 = (const float*)d_in[9];
    const float* wn2 = (const float*)d_in[10];
    const float* b2  = (const float*)d_in[11];

    char* ws = (char*)d_ws;
    size_t o = 0;
    auto alloc = [&](size_t bytes) { size_t r = o; o = (o + bytes + 255) & ~(size_t)255; return r; };
    int* deg        = (int*)(ws + alloc((size_t)N_NODES * 4));
    int* row_start  = (int*)(ws + alloc((size_t)(N_NODES + 1) * 4));
    int* cursor     = (int*)(ws + alloc((size_t)N_NODES * 4));
    int* bsums      = (int*)(ws + alloc(512 * 4));
    int* col        = (int*)(ws + alloc((size_t)N_EDGES * 4));
    ushort_t* wt0   = (ushort_t*)(ws + alloc(128 * 256 * 2));
    ushort_t* wt1   = (ushort_t*)(ws + alloc(128 * 256 * 2));
    ushort_t* wt2   = (ushort_t*)(ws + alloc(64 * 256 * 2));
    ushort_t* hA    = (ushort_t*)(ws + alloc((size_t)N_NODES * 128 * 2));
    ushort_t* hB    = (ushort_t*)(ws + alloc((size_t)N_NODES * 128 * 2));
    ushort_t* hngh  = (ushort_t*)(ws + alloc((size_t)N_NODES * 128 * 2));
    (void)ws_size;

    const int NB_SCAN = (N_NODES + 255) / 256;   // 391

    hipMemsetAsync(deg, 0, (size_t)N_NODES * 4, stream);
    k_hist<<<N_EDGES / 256, 256, 0, stream>>>(dst, deg);
    k_block_reduce<<<NB_SCAN, 256, 0, stream>>>(deg, bsums);
    k_top_scan<<<1, 512, 0, stream>>>(bsums, NB_SCAN);
    k_scan_final<<<NB_SCAN, 256, 0, stream>>>(deg, bsums, row_start, cursor);
    k_fill<<<N_EDGES / 256, 256, 0, stream>>>(src, dst, cursor, col);

    k_cvt_x<<<(N_NODES * 128 / 4) / 256, 256, 0, stream>>>(x, hA);
    k_cvt_w<<<320, 256, 0, stream>>>(ws0, wn0, ws1, wn1, ws2, wn2, wt0, wt1, wt2);

    const int GEMM_GRID = (N_NODES + 63) / 64;   // 1563

    // layer 0: hA -> hB
    k_agg<<<N_NODES / 4, 256, 0, stream>>>(hA, row_start, col, hngh);
    k_gemm<128, true, false><<<GEMM_GRID, 256, 0, stream>>>(hA, hngh, wt0, b0, hB, nullptr);
    // layer 1: hB -> hA
    k_agg<<<N_NODES / 4, 256, 0, stream>>>(hB, row_start, col, hngh);
    k_gemm<128, true, false><<<GEMM_GRID, 256, 0, stream>>>(hB, hngh, wt1, b1, hA, nullptr);
    // layer 2: hA -> out (f32)
    k_agg<<<N_NODES / 4, 256, 0, stream>>>(hA, row_start, col, hngh);
    k_gemm<64, false, true><<<GEMM_GRID, 256, 0, stream>>>(hA, hngh, wt2, b2, nullptr, (float*)d_out);
}